// Round 15
// baseline (21.150 us; speedup 1.0000x reference)
//
#include <hip/hip_runtime.h>
#include <float.h>
#include <math.h>

// Problem constants (from reference)
constexpr int B  = 16;
constexpr int VS = 10475;
constexpr int VO = 8192;
constexpr int K  = 64;
constexpr int PS = 1024;
constexpr int PO = 2048;

// R15: R14 skeleton (256 blocks x 1024 threads = 16 waves/CU, single
// gather, proven 19.4us) with ONE change: HALF-WAVE jgroups.
//   NG=32 groups x JPG=64 objects, QL=8 queries/lane (4 packed pairs).
// Wave-level ds_read count halves vs R14 (PO/2 = 1024 2-addr reads per
// block instead of 2048 1-addr reads); 2-addr reads are conflict-free
// (2 lanes/bank is free per m136). VALU count unchanged.
constexpr int BLK  = 1024;
constexpr int QPB  = 256;              // queries per block
constexpr int GRID = K * (PS / QPB);   // 256
constexpr int NG   = 32;               // jgroups (half-waves) per block
constexpr int JPG  = PO / NG;          // 64 objects per jgroup
constexpr int QL   = 8;                // queries per lane (4 packed pairs)

typedef float v2f __attribute__((ext_vector_type(2)));
typedef float v4f __attribute__((ext_vector_type(4)));

// ---------------- kernel 1: full min + block partial sum ----------------

__global__ __launch_bounds__(BLK)
void cl_onepass(const float* __restrict__ smplx_v,
                const float* __restrict__ object_v,
                const int*   __restrict__ spi,
                const int*   __restrict__ opi,
                const int*   __restrict__ bidx,
                float*       __restrict__ partial)   // [GRID]
{
    __shared__ v4f    so[PO];        // (x,y,z, 0.5*|o|^2) -> 32 KiB
    __shared__ float4 qld[QPB];      // (x,y,z, |s|^2)     ->  4 KiB
    __shared__ float  red[NG][QPB];  //                    -> 32 KiB
    __shared__ float  wsum[BLK / 64];//                    -> 64 B

    const int bk  = blockIdx.x;
    const int tid = threadIdx.x;
    const int k   = bk >> 2;
    const int ic  = bk & 3;
    const int b   = bidx[k];

    // ---- gather: all 2048 objects, 2 per thread (16 waves overlap) ----
    const float* __restrict__ ov = object_v + (size_t)b * VO * 3;
    #pragma unroll
    for (int r = 0; r < PO / BLK; ++r) {
        const int j  = r * BLK + tid;
        const int oj = opi[k * PO + j];
        const float x = ov[oj * 3 + 0];
        const float y = ov[oj * 3 + 1];
        const float z = ov[oj * 3 + 2];
        so[j] = (v4f){x, y, z, 0.5f * (x * x + y * y + z * z)};
    }
    // ---- gather: this block's 256 queries (waves 0-3) ----
    if (tid < QPB) {
        const int i  = ic * QPB + tid;
        const int si = spi[k * PS + i];
        const float* __restrict__ sv = smplx_v + ((size_t)b * VS + si) * 3;
        const float x = sv[0], y = sv[1], z = sv[2];
        qld[tid] = make_float4(x, y, z, x * x + y * y + z * z);
    }
    __syncthreads();

    // ---- setup: lane owns 8 queries as 4 packed pairs ----
    const int g  = tid >> 5;         // jgroup 0..31 (half-wave)
    const int gl = tid & 31;
    const int qb = gl * QL;

    v2f nsx[4], nsy[4], nsz[4], mint[4];
    #pragma unroll
    for (int p = 0; p < 4; ++p) {
        const float4 qa = qld[qb + 2 * p];
        const float4 qc = qld[qb + 2 * p + 1];
        nsx[p] = (v2f){-qa.x, -qc.x};
        nsy[p] = (v2f){-qa.y, -qc.y};
        nsz[p] = (v2f){-qa.z, -qc.z};
        mint[p] = (v2f){FLT_MAX, FLT_MAX};
    }

    // ---- hot loop (R6-proven asm): this group's 64 objects ----
    // t = 0.5*|o|^2 - s.o for 2 queries per v_pk_fma_f32; op_sel splats the
    // object components straight out of the (x,y),(z,w) register pairs.
    const v4f* __restrict__ sog = &so[g * JPG];
    #pragma unroll 8
    for (int j = 0; j < JPG; ++j) {
        const v4f o = sog[j];
        const v2f oxy = __builtin_shufflevector(o, o, 0, 1);  // (x,y)
        const v2f ozw = __builtin_shufflevector(o, o, 2, 3);  // (z,w)
        #pragma unroll
        for (int p = 0; p < 4; ++p) {
            v2f t;
            asm("v_pk_fma_f32 %0, %1, %2, %3 op_sel:[0,0,1] op_sel_hi:[0,1,1]"
                : "=v"(t) : "v"(oxy), "v"(nsx[p]), "v"(ozw));
            asm("v_pk_fma_f32 %0, %1, %2, %0 op_sel:[1,0,0] op_sel_hi:[1,1,1]"
                : "+v"(t) : "v"(oxy), "v"(nsy[p]));
            asm("v_pk_fma_f32 %0, %1, %2, %0 op_sel:[0,0,0] op_sel_hi:[0,1,1]"
                : "+v"(t) : "v"(ozw), "v"(nsz[p]));
            mint[p].x = fminf(mint[p].x, t.x);
            mint[p].y = fminf(mint[p].y, t.y);
        }
    }

    // ---- cross-jgroup min via LDS ----
    #pragma unroll
    for (int p = 0; p < 4; ++p) {
        red[g][qb + 2 * p]     = mint[p].x;
        red[g][qb + 2 * p + 1] = mint[p].y;
    }
    __syncthreads();

    // ---- finalize query tid (waves 0-3); 2-level wave reduce ----
    float d = 0.0f;
    if (tid < QPB) {
        float mq = red[0][tid];
        #pragma unroll
        for (int g2 = 1; g2 < NG; ++g2) mq = fminf(mq, red[g2][tid]);
        const float s2q = qld[tid].w;
        d = sqrtf(fmaxf(fmaf(2.0f, mq, s2q), 0.0f));
    }
    #pragma unroll
    for (int off = 32; off > 0; off >>= 1)
        d += __shfl_down(d, off, 64);
    const int wv = tid >> 6;         // wave id 0..15
    if ((tid & 63) == 0) wsum[wv] = d;   // waves 4-15 contribute 0
    __syncthreads();
    if (tid < 64) {
        float v = (tid < BLK / 64) ? wsum[tid] : 0.0f;
        #pragma unroll
        for (int off = 8; off > 0; off >>= 1)
            v += __shfl_down(v, off, 64);
        if (tid == 0) partial[bk] = v;
    }
}

// ---------------- kernel 2: final 256 -> 1 reduce (one wave) ----------------

__global__ __launch_bounds__(64)
void cl_final(const float* __restrict__ partial, float* __restrict__ out)
{
    const int t = threadIdx.x;
    const float4 a = ((const float4*)partial)[t];   // 64 lanes x 4 = 256
    float v = (a.x + a.y) + (a.z + a.w);
    #pragma unroll
    for (int off = 32; off > 0; off >>= 1)
        v += __shfl_down(v, off, 64);
    if (t == 0) out[0] = v * (1.0f / (float)(K * PS));
}

// ---------------- launcher ----------------

extern "C" void kernel_launch(void* const* d_in, const int* in_sizes, int n_in,
                              void* d_out, int out_size, void* d_ws, size_t ws_size,
                              hipStream_t stream)
{
    const float* smplx_v       = (const float*)d_in[0];
    const float* object_v      = (const float*)d_in[1];
    const int*   smpl_part_idx = (const int*)d_in[2];
    const int*   obj_part_idx  = (const int*)d_in[3];
    const int*   batch_idx     = (const int*)d_in[4];
    float*       out           = (float*)d_out;

    float* partial = (float*)d_ws;   // GRID floats

    cl_onepass<<<GRID, BLK, 0, stream>>>(
        smplx_v, object_v, smpl_part_idx, obj_part_idx, batch_idx, partial);
    cl_final<<<1, 64, 0, stream>>>(partial, out);
}

// Round 16
// 19.158 us; speedup vs baseline: 1.1040x; 1.1040x over previous
//
#include <hip/hip_runtime.h>
#include <float.h>
#include <math.h>

// Problem constants (from reference)
constexpr int B  = 16;
constexpr int VS = 10475;
constexpr int VO = 8192;
constexpr int K  = 64;
constexpr int PS = 1024;
constexpr int PO = 2048;

// R16 = R14 (proven 19.4us: 256 blocks x 1024 thr = 16 waves/CU, single
// gather, full-wave broadcast jgroups NG=16 x 128 obj, QL=4) with ONE
// change: gathered points loaded as <3 x float> (global_load_dwordx3,
// 1 divergent load per point instead of 3 -> ~1/3 the L1 transactions).
constexpr int BLK  = 1024;
constexpr int QPB  = 256;              // queries per block
constexpr int GRID = K * (PS / QPB);   // 256
constexpr int NG   = 16;               // jgroups = waves per block
constexpr int JPG  = PO / NG;          // 128 objects per jgroup
constexpr int QL   = 4;                // queries per lane (2 packed pairs)

typedef float v2f __attribute__((ext_vector_type(2)));
typedef float v3f __attribute__((ext_vector_type(3)));
typedef float v4f __attribute__((ext_vector_type(4)));

// ---------------- kernel 1: full min + block partial sum ----------------

__global__ __launch_bounds__(BLK)
void cl_onepass(const float* __restrict__ smplx_v,
                const float* __restrict__ object_v,
                const int*   __restrict__ spi,
                const int*   __restrict__ opi,
                const int*   __restrict__ bidx,
                float*       __restrict__ partial)   // [GRID]
{
    __shared__ v4f    so[PO];        // (x,y,z, 0.5*|o|^2) -> 32 KiB
    __shared__ float4 qld[QPB];      // (x,y,z, |s|^2)     ->  4 KiB
    __shared__ float  red[NG][QPB];  //                    -> 16 KiB
    __shared__ float  wsum[NG];      //                    -> 64 B

    const int bk  = blockIdx.x;
    const int tid = threadIdx.x;
    const int k   = bk >> 2;
    const int ic  = bk & 3;
    const int b   = bidx[k];

    // ---- gather: all 2048 objects, 2 per thread, ONE dwordx3 per point ----
    const float* __restrict__ ov = object_v + (size_t)b * VO * 3;
    #pragma unroll
    for (int r = 0; r < PO / BLK; ++r) {
        const int j  = r * BLK + tid;
        const int oj = opi[k * PO + j];
        const v3f p  = *(const v3f*)(ov + 3 * (size_t)oj);
        so[j] = (v4f){p.x, p.y, p.z, 0.5f * (p.x * p.x + p.y * p.y + p.z * p.z)};
    }
    // ---- gather: this block's 256 queries (waves 0-3), dwordx3 ----
    if (tid < QPB) {
        const int i  = ic * QPB + tid;
        const int si = spi[k * PS + i];
        const v3f s  = *(const v3f*)(smplx_v + 3 * ((size_t)b * VS + si));
        qld[tid] = make_float4(s.x, s.y, s.z, s.x * s.x + s.y * s.y + s.z * s.z);
    }
    __syncthreads();

    // ---- setup: lane owns 4 queries as 2 packed pairs (R14-identical) ----
    const int g    = tid >> 6;       // jgroup == wave id (0..15)
    const int lane = tid & 63;
    const int qb   = lane * QL;

    v2f nsx[2], nsy[2], nsz[2], mint[2];
    #pragma unroll
    for (int p = 0; p < 2; ++p) {
        const float4 qa = qld[qb + 2 * p];
        const float4 qc = qld[qb + 2 * p + 1];
        nsx[p] = (v2f){-qa.x, -qc.x};
        nsy[p] = (v2f){-qa.y, -qc.y};
        nsz[p] = (v2f){-qa.z, -qc.z};
        mint[p] = (v2f){FLT_MAX, FLT_MAX};
    }

    // ---- hot loop (R6-proven asm): this wave's 128 objects, broadcast ----
    const v4f* __restrict__ sog = &so[g * JPG];
    #pragma unroll 8
    for (int j = 0; j < JPG; ++j) {
        const v4f o = sog[j];
        const v2f oxy = __builtin_shufflevector(o, o, 0, 1);  // (x,y)
        const v2f ozw = __builtin_shufflevector(o, o, 2, 3);  // (z,w)
        #pragma unroll
        for (int p = 0; p < 2; ++p) {
            v2f t;
            asm("v_pk_fma_f32 %0, %1, %2, %3 op_sel:[0,0,1] op_sel_hi:[0,1,1]"
                : "=v"(t) : "v"(oxy), "v"(nsx[p]), "v"(ozw));
            asm("v_pk_fma_f32 %0, %1, %2, %0 op_sel:[1,0,0] op_sel_hi:[1,1,1]"
                : "+v"(t) : "v"(oxy), "v"(nsy[p]));
            asm("v_pk_fma_f32 %0, %1, %2, %0 op_sel:[0,0,0] op_sel_hi:[0,1,1]"
                : "+v"(t) : "v"(ozw), "v"(nsz[p]));
            mint[p].x = fminf(mint[p].x, t.x);
            mint[p].y = fminf(mint[p].y, t.y);
        }
    }

    // ---- cross-jgroup min via LDS (R14-identical) ----
    #pragma unroll
    for (int p = 0; p < 2; ++p) {
        red[g][qb + 2 * p]     = mint[p].x;
        red[g][qb + 2 * p + 1] = mint[p].y;
    }
    __syncthreads();

    // ---- finalize query tid (waves 0-3); 2-level wave reduce ----
    float d = 0.0f;
    if (tid < QPB) {
        float mq = red[0][tid];
        #pragma unroll
        for (int g2 = 1; g2 < NG; ++g2) mq = fminf(mq, red[g2][tid]);
        const float s2q = qld[tid].w;
        d = sqrtf(fmaxf(fmaf(2.0f, mq, s2q), 0.0f));
    }
    #pragma unroll
    for (int off = 32; off > 0; off >>= 1)
        d += __shfl_down(d, off, 64);
    if (lane == 0) wsum[g] = d;     // waves 4-15 contribute 0
    __syncthreads();
    if (tid < 64) {
        float v = (tid < NG) ? wsum[tid] : 0.0f;
        #pragma unroll
        for (int off = 8; off > 0; off >>= 1)
            v += __shfl_down(v, off, 64);
        if (tid == 0) partial[bk] = v;
    }
}

// ---------------- kernel 2: final 256 -> 1 reduce (one wave) ----------------

__global__ __launch_bounds__(64)
void cl_final(const float* __restrict__ partial, float* __restrict__ out)
{
    const int t = threadIdx.x;
    const float4 a = ((const float4*)partial)[t];   // 64 lanes x 4 = 256
    float v = (a.x + a.y) + (a.z + a.w);
    #pragma unroll
    for (int off = 32; off > 0; off >>= 1)
        v += __shfl_down(v, off, 64);
    if (t == 0) out[0] = v * (1.0f / (float)(K * PS));
}

// ---------------- launcher ----------------

extern "C" void kernel_launch(void* const* d_in, const int* in_sizes, int n_in,
                              void* d_out, int out_size, void* d_ws, size_t ws_size,
                              hipStream_t stream)
{
    const float* smplx_v       = (const float*)d_in[0];
    const float* object_v      = (const float*)d_in[1];
    const int*   smpl_part_idx = (const int*)d_in[2];
    const int*   obj_part_idx  = (const int*)d_in[3];
    const int*   batch_idx     = (const int*)d_in[4];
    float*       out           = (float*)d_out;

    float* partial = (float*)d_ws;   // GRID floats

    cl_onepass<<<GRID, BLK, 0, stream>>>(
        smplx_v, object_v, smpl_part_idx, obj_part_idx, batch_idx, partial);
    cl_final<<<1, 64, 0, stream>>>(partial, out);
}

// Round 17
// 19.012 us; speedup vs baseline: 1.1124x; 1.0076x over previous
//
#include <hip/hip_runtime.h>
#include <float.h>
#include <math.h>

// Problem constants (from reference)
constexpr int B  = 16;
constexpr int VS = 10475;
constexpr int VO = 8192;
constexpr int K  = 64;
constexpr int PS = 1024;
constexpr int PO = 2048;

// R17 = R16 (19.16us: 256 blocks x 1024 thr = 16 waves/CU, full-wave
// broadcast jgroups, dwordx3 gather, QL=4) + DOUBLE-BUFFERED object gather:
// half-1's global loads are issued before computing half-0, so the VMEM
// phase overlaps the VALU/LDS hot loop (R10's structure WITHOUT the
// min3-pairing that caused its regression).
constexpr int BLK  = 1024;
constexpr int QPB  = 256;              // queries per block
constexpr int GRID = K * (PS / QPB);   // 256
constexpr int NG   = 16;               // jgroups = waves per block
constexpr int HALF = PO / 2;           // 1024 objects per half (1/thread)
constexpr int JPH  = HALF / NG;        // 64 objects per wave per half
constexpr int QL   = 4;                // queries per lane (2 packed pairs)

typedef float v2f __attribute__((ext_vector_type(2)));
typedef float v3f __attribute__((ext_vector_type(3)));
typedef float v4f __attribute__((ext_vector_type(4)));

// ---------------- kernel 1: full min + block partial sum ----------------

__global__ __launch_bounds__(BLK)
void cl_onepass(const float* __restrict__ smplx_v,
                const float* __restrict__ object_v,
                const int*   __restrict__ spi,
                const int*   __restrict__ opi,
                const int*   __restrict__ bidx,
                float*       __restrict__ partial)   // [GRID]
{
    __shared__ v4f    soA[HALF];     // 16 KiB  (x,y,z, 0.5*|o|^2)
    __shared__ v4f    soB[HALF];     // 16 KiB
    __shared__ float4 qld[QPB];      //  4 KiB  (x,y,z, |s|^2)
    __shared__ float  red[NG][QPB];  // 16 KiB
    __shared__ float  wsum[NG];      //  64 B

    const int bk  = blockIdx.x;
    const int tid = threadIdx.x;
    const int k   = bk >> 2;
    const int ic  = bk & 3;
    const int b   = bidx[k];

    const float* __restrict__ ov   = object_v + (size_t)b * VO * 3;
    const int*   __restrict__ opik = opi + k * PO;

    // ---- half-0 object gather (1 point/thread, dwordx3) ----
    {
        const int oj = opik[tid];
        const v3f p  = *(const v3f*)(ov + 3 * (size_t)oj);
        soA[tid] = (v4f){p.x, p.y, p.z,
                         0.5f * (p.x * p.x + p.y * p.y + p.z * p.z)};
    }
    // ---- query gather (waves 0-3, dwordx3) ----
    if (tid < QPB) {
        const int i  = ic * QPB + tid;
        const int si = spi[k * PS + i];
        const v3f s  = *(const v3f*)(smplx_v + 3 * ((size_t)b * VS + si));
        qld[tid] = make_float4(s.x, s.y, s.z,
                               s.x * s.x + s.y * s.y + s.z * s.z);
    }
    __syncthreads();

    // ---- issue half-1 loads (stay in flight under half-0 compute) ----
    v3f p1;
    {
        const int oj = opik[HALF + tid];
        p1 = *(const v3f*)(ov + 3 * (size_t)oj);
    }

    // ---- setup: lane owns 4 queries as 2 packed pairs (R16-identical) ----
    const int g    = tid >> 6;       // jgroup == wave id (0..15)
    const int lane = tid & 63;
    const int qb   = lane * QL;

    v2f nsx[2], nsy[2], nsz[2], mint[2];
    #pragma unroll
    for (int p = 0; p < 2; ++p) {
        const float4 qa = qld[qb + 2 * p];
        const float4 qc = qld[qb + 2 * p + 1];
        nsx[p] = (v2f){-qa.x, -qc.x};
        nsy[p] = (v2f){-qa.y, -qc.y};
        nsz[p] = (v2f){-qa.z, -qc.z};
        mint[p] = (v2f){FLT_MAX, FLT_MAX};
    }

    // ---- hot loop body (R6-proven asm, byte-identical) ----
    #define CL_BODY(SOH)                                                      \
    {                                                                         \
        const v4f* __restrict__ sog = &(SOH)[g * JPH];                        \
        _Pragma("unroll 8")                                                   \
        for (int j = 0; j < JPH; ++j) {                                       \
            const v4f o = sog[j];                                             \
            const v2f oxy = __builtin_shufflevector(o, o, 0, 1);              \
            const v2f ozw = __builtin_shufflevector(o, o, 2, 3);              \
            _Pragma("unroll")                                                 \
            for (int p = 0; p < 2; ++p) {                                     \
                v2f t;                                                        \
                asm("v_pk_fma_f32 %0, %1, %2, %3 op_sel:[0,0,1] op_sel_hi:[0,1,1]" \
                    : "=v"(t) : "v"(oxy), "v"(nsx[p]), "v"(ozw));             \
                asm("v_pk_fma_f32 %0, %1, %2, %0 op_sel:[1,0,0] op_sel_hi:[1,1,1]" \
                    : "+v"(t) : "v"(oxy), "v"(nsy[p]));                       \
                asm("v_pk_fma_f32 %0, %1, %2, %0 op_sel:[0,0,0] op_sel_hi:[0,1,1]" \
                    : "+v"(t) : "v"(ozw), "v"(nsz[p]));                       \
                mint[p].x = fminf(mint[p].x, t.x);                            \
                mint[p].y = fminf(mint[p].y, t.y);                            \
            }                                                                 \
        }                                                                     \
    }

    CL_BODY(soA)                     // half-0 compute; half-1 loads in flight

    // ---- write half-1 (waitcnt lands here, after half-0 compute) ----
    soB[tid] = (v4f){p1.x, p1.y, p1.z,
                     0.5f * (p1.x * p1.x + p1.y * p1.y + p1.z * p1.z)};
    __syncthreads();

    CL_BODY(soB)                     // half-1 compute
    #undef CL_BODY

    // ---- cross-jgroup min via LDS (R16-identical) ----
    #pragma unroll
    for (int p = 0; p < 2; ++p) {
        red[g][qb + 2 * p]     = mint[p].x;
        red[g][qb + 2 * p + 1] = mint[p].y;
    }
    __syncthreads();

    // ---- finalize query tid (waves 0-3); 2-level wave reduce ----
    float d = 0.0f;
    if (tid < QPB) {
        float mq = red[0][tid];
        #pragma unroll
        for (int g2 = 1; g2 < NG; ++g2) mq = fminf(mq, red[g2][tid]);
        const float s2q = qld[tid].w;
        d = sqrtf(fmaxf(fmaf(2.0f, mq, s2q), 0.0f));
    }
    #pragma unroll
    for (int off = 32; off > 0; off >>= 1)
        d += __shfl_down(d, off, 64);
    if (lane == 0) wsum[g] = d;     // waves 4-15 contribute 0
    __syncthreads();
    if (tid < 64) {
        float v = (tid < NG) ? wsum[tid] : 0.0f;
        #pragma unroll
        for (int off = 8; off > 0; off >>= 1)
            v += __shfl_down(v, off, 64);
        if (tid == 0) partial[bk] = v;
    }
}

// ---------------- kernel 2: final 256 -> 1 reduce (one wave) ----------------

__global__ __launch_bounds__(64)
void cl_final(const float* __restrict__ partial, float* __restrict__ out)
{
    const int t = threadIdx.x;
    const float4 a = ((const float4*)partial)[t];   // 64 lanes x 4 = 256
    float v = (a.x + a.y) + (a.z + a.w);
    #pragma unroll
    for (int off = 32; off > 0; off >>= 1)
        v += __shfl_down(v, off, 64);
    if (t == 0) out[0] = v * (1.0f / (float)(K * PS));
}

// ---------------- launcher ----------------

extern "C" void kernel_launch(void* const* d_in, const int* in_sizes, int n_in,
                              void* d_out, int out_size, void* d_ws, size_t ws_size,
                              hipStream_t stream)
{
    const float* smplx_v       = (const float*)d_in[0];
    const float* object_v      = (const float*)d_in[1];
    const int*   smpl_part_idx = (const int*)d_in[2];
    const int*   obj_part_idx  = (const int*)d_in[3];
    const int*   batch_idx     = (const int*)d_in[4];
    float*       out           = (float*)d_out;

    float* partial = (float*)d_ws;   // GRID floats

    cl_onepass<<<GRID, BLK, 0, stream>>>(
        smplx_v, object_v, smpl_part_idx, obj_part_idx, batch_idx, partial);
    cl_final<<<1, 64, 0, stream>>>(partial, out);
}

// Round 18
// 16.511 us; speedup vs baseline: 1.2810x; 1.1515x over previous
//
#include <hip/hip_runtime.h>
#include <float.h>
#include <math.h>

// Problem constants (from reference)
constexpr int B  = 16;
constexpr int VS = 10475;
constexpr int VO = 8192;
constexpr int K  = 64;
constexpr int PS = 1024;
constexpr int PO = 2048;

// R18: MFMA hot loop. 256 blocks x 1024 thr (16 waves/CU). Block = (k,
// 256-query chunk); wave = 16-query tile x all 2048 objects (128 obj tiles).
// Per tile: ONE v_mfma_f32_16x16x32_f16 computes dot = s.o_hat - 0.5|o_hat|^2
// for all 256 pairs (A row = [hi(s),-1,lo(s),-1], B col = [o,w2h,o,w2l]),
// then 4 v_min (negated) accumulate the running min. Queries split hi+lo
// (exact to 2^-22); objects fp16-rounded (distance err ~5e-4, loss bias
// ~1e-3 << 4e-3 threshold).
constexpr int BLK  = 1024;
constexpr int QPB  = 256;              // queries per block
constexpr int GRID = K * (PS / QPB);   // 256
constexpr int NW   = 16;               // waves per block
constexpr int NT   = PO / 16;          // 128 object tiles per wave

typedef float  v3f  __attribute__((ext_vector_type(3)));
typedef float  f32x4 __attribute__((ext_vector_type(4)));
typedef _Float16 half8 __attribute__((ext_vector_type(8)));
typedef unsigned int u32;
typedef u32 v4u  __attribute__((ext_vector_type(4)));

__device__ __forceinline__ u32 pkh(_Float16 lo, _Float16 hi) {
    const unsigned short l = __builtin_bit_cast(unsigned short, lo);
    const unsigned short h = __builtin_bit_cast(unsigned short, hi);
    return ((u32)h << 16) | (u32)l;
}

// ---------------- kernel 1: full min + block partial sum ----------------

__global__ __launch_bounds__(BLK)
void cl_onepass(const float* __restrict__ smplx_v,
                const float* __restrict__ object_v,
                const int*   __restrict__ spi,
                const int*   __restrict__ opi,
                const int*   __restrict__ bidx,
                float*       __restrict__ partial)   // [GRID]
{
    // Object entry e = 8 fp16 (16 B): [ox,oy,oz,w2h, ox,oy,oz,w2l]
    // (k0..7 of the B fragment). +16 zero entries for lanes>=16.
    __shared__ u32   so[(PO + 16) * 4];   // 33 KiB
    __shared__ float wsum[NW];

    const int bk   = blockIdx.x;
    const int tid  = threadIdx.x;
    const int k    = bk >> 2;
    const int ic   = bk & 3;
    const int b    = bidx[k];
    const int wave = tid >> 6;
    const int lane = tid & 63;

    // ---- stage objects: 2 per thread, fp16-rounded + 0.5|o|^2 split ----
    const float* __restrict__ ov = object_v + (size_t)b * VO * 3;
    #pragma unroll
    for (int r = 0; r < PO / BLK; ++r) {
        const int j  = r * BLK + tid;
        const int oj = opi[k * PO + j];
        const v3f p  = *(const v3f*)(ov + 3 * (size_t)oj);
        const _Float16 hx = (_Float16)p.x, hy = (_Float16)p.y, hz = (_Float16)p.z;
        const float fx = (float)hx, fy = (float)hy, fz = (float)hz;
        const float w2 = 0.5f * (fx * fx + fy * fy + fz * fz);
        const _Float16 w2h = (_Float16)w2;
        const _Float16 w2l = (_Float16)(w2 - (float)w2h);
        const u32 d0 = pkh(hx, hy);
        *(v4u*)&so[j * 4] = (v4u){d0, pkh(hz, w2h), d0, pkh(hz, w2l)};
    }
    // zero pad entries PO..PO+15 (64 dwords)
    if (tid < 64) so[PO * 4 + tid] = 0;

    // ---- load queries: lanes 0-15 of each wave own one query (= A row) ----
    half8 afrag = (half8)(_Float16)0;
    float s2 = 0.0f;
    if (lane < 16) {
        const int i  = ic * QPB + wave * 16 + lane;
        const int si = spi[k * PS + i];
        const v3f s  = *(const v3f*)(smplx_v + 3 * ((size_t)b * VS + si));
        s2 = s.x * s.x + s.y * s.y + s.z * s.z;
        const _Float16 shx = (_Float16)s.x, shy = (_Float16)s.y, shz = (_Float16)s.z;
        const _Float16 slx = (_Float16)(s.x - (float)shx);
        const _Float16 sly = (_Float16)(s.y - (float)shy);
        const _Float16 slz = (_Float16)(s.z - (float)shz);
        const _Float16 n1  = (_Float16)(-1.0f);
        afrag = (half8){shx, shy, shz, n1, slx, sly, slz, n1};
    }
    __syncthreads();

    // ---- per-lane B-fragment pointer (lanes>=16 read the zero pad) ----
    const u32* bp = (lane < 16) ? &so[lane * 4]
                                : &so[PO * 4 + (lane & 15) * 4];
    const int  inc = (lane < 16) ? 64 : 0;   // u32 stride per tile

    // ---- hot loop: 128 tiles, 1 MFMA + 4 negated v_min each ----
    f32x4 mint = (f32x4){FLT_MAX, FLT_MAX, FLT_MAX, FLT_MAX};
    #pragma unroll 8
    for (int t = 0; t < NT; ++t) {
        const half8 bfrag = *(const half8*)bp;
        const f32x4 d = __builtin_amdgcn_mfma_f32_16x16x32_f16(
            afrag, bfrag, (f32x4){0.f, 0.f, 0.f, 0.f}, 0, 0, 0);
        mint.x = fminf(mint.x, -d.x);
        mint.y = fminf(mint.y, -d.y);
        mint.z = fminf(mint.z, -d.z);
        mint.w = fminf(mint.w, -d.w);
        bp += inc;
    }

    // ---- min over the 16 columns (lanes sharing lane>>4) ----
    #pragma unroll
    for (int m = 1; m <= 8; m <<= 1) {
        mint.x = fminf(mint.x, __shfl_xor(mint.x, m, 64));
        mint.y = fminf(mint.y, __shfl_xor(mint.y, m, 64));
        mint.z = fminf(mint.z, __shfl_xor(mint.z, m, 64));
        mint.w = fminf(mint.w, __shfl_xor(mint.w, m, 64));
    }

    // ---- route row minima to lanes 0-15 (row l held by lane (l>>2)*16) ----
    const int src = (lane >> 2) << 4;
    const float t0 = __shfl(mint.x, src, 64);
    const float t1 = __shfl(mint.y, src, 64);
    const float t2 = __shfl(mint.z, src, 64);
    const float t3 = __shfl(mint.w, src, 64);
    const int rsel = lane & 3;
    const float tmy = (rsel == 0) ? t0 : (rsel == 1) ? t1 : (rsel == 2) ? t2 : t3;

    float d = 0.0f;
    if (lane < 16)
        d = sqrtf(fmaxf(fmaf(2.0f, tmy, s2), 0.0f));

    // ---- wave sum (lanes 0-15 carry values, rest zero) ----
    #pragma unroll
    for (int m = 1; m <= 8; m <<= 1)
        d += __shfl_xor(d, m, 64);
    if (lane == 0) wsum[wave] = d;
    __syncthreads();

    if (tid < 64) {
        float v = (tid < NW) ? wsum[tid] : 0.0f;
        #pragma unroll
        for (int off = 8; off > 0; off >>= 1)
            v += __shfl_down(v, off, 64);
        if (tid == 0) partial[bk] = v;
    }
}

// ---------------- kernel 2: final 256 -> 1 reduce (one wave) ----------------

__global__ __launch_bounds__(64)
void cl_final(const float* __restrict__ partial, float* __restrict__ out)
{
    const int t = threadIdx.x;
    const float4 a = ((const float4*)partial)[t];   // 64 lanes x 4 = 256
    float v = (a.x + a.y) + (a.z + a.w);
    #pragma unroll
    for (int off = 32; off > 0; off >>= 1)
        v += __shfl_down(v, off, 64);
    if (t == 0) out[0] = v * (1.0f / (float)(K * PS));
}

// ---------------- launcher ----------------

extern "C" void kernel_launch(void* const* d_in, const int* in_sizes, int n_in,
                              void* d_out, int out_size, void* d_ws, size_t ws_size,
                              hipStream_t stream)
{
    const float* smplx_v       = (const float*)d_in[0];
    const float* object_v      = (const float*)d_in[1];
    const int*   smpl_part_idx = (const int*)d_in[2];
    const int*   obj_part_idx  = (const int*)d_in[3];
    const int*   batch_idx     = (const int*)d_in[4];
    float*       out           = (float*)d_out;

    float* partial = (float*)d_ws;   // GRID floats

    cl_onepass<<<GRID, BLK, 0, stream>>>(
        smplx_v, object_v, smpl_part_idx, obj_part_idx, batch_idx, partial);
    cl_final<<<1, 64, 0, stream>>>(partial, out);
}